// Round 21
// baseline (73.115 us; speedup 1.0000x reference)
//
#include <hip/hip_runtime.h>

#define BATCH 128
#define LEN 512
#define NCHUNK 4              // quarters per batch (kernel-2 view)
#define SIG_DIM 4680          // 8 + 64 + 512 + 4096
#define N_OUT 10
// thin sig offsets (global layout, W indexing)
#define OFF2 8
#define OFF3 72
#define OFF4 584
// FATPAD v2 LDS sig buffer: B1[8] | B2[64] | B3[64 rows x 12 pad, rows
// bit-swap-permuted] | B4[64 rows x 68 pad]. All row reads/writes are
// conflict-free ds_read/write_b128 (12*j mod 32 and 68*lane mod 32 both
// enumerate the 8 four-bank groups).
#define B2OFF 8
#define B3OFF 72
#define B4OFF 840
#define BUFSZ 5192            // 8 + 64 + 768 + 4352

typedef float v4f __attribute__((ext_vector_type(4)));

__device__ __forceinline__ int b3row(int r) {      // bit-swapped B3 row perm
    return ((r & 7) << 3) | (r >> 3);
}

// stage a fat-layout signature (lane=(i,j) owns s2, s3[k], s4[k][l]) into a
// FATPAD v2 LDS buffer. b128 writes throughout.
__device__ __forceinline__ void stage_fat(float* __restrict__ buf,
                                          float s1, float s2,
                                          const float s3[8], const float s4[8][8],
                                          int lane) {
    if ((lane & 7) == 0) buf[lane >> 3] = s1;          // B1[i] (j==0 canonical)
    buf[B2OFF + lane] = s2;                            // B2[ij]
    const int pr = b3row(lane);
    *(float4*)&buf[B3OFF + pr * 12]     = make_float4(s3[0], s3[1], s3[2], s3[3]);
    *(float4*)&buf[B3OFF + pr * 12 + 4] = make_float4(s3[4], s3[5], s3[6], s3[7]);
    #pragma unroll
    for (int k = 0; k < 8; ++k) {
        float* dst = &buf[B4OFF + lane * 68 + k * 8];
        *(float4*)dst       = make_float4(s4[k][0], s4[k][1], s4[k][2], s4[k][3]);
        *(float4*)(dst + 4) = make_float4(s4[k][4], s4[k][5], s4[k][6], s4[k][7]);
    }
}

// Chen combine in fat layout: A (regs, earlier chunk) ∘= B (FATPAD v2 LDS).
// Identical arithmetic to the R16-verified version; only addressing changed
// (B3 transposed rows + stride 12, B4 stride 68) to enable b128 reads.
__device__ __forceinline__ void combine_fat(float& A1, float& A2,
                                            float A3[8], float A4[8][8],
                                            const float* __restrict__ buf,
                                            int i, int j, int lane) {
    const float4 b1a = *(const float4*)&buf[0];
    const float4 b1b = *(const float4*)&buf[4];
    const float B1[8] = {b1a.x, b1a.y, b1a.z, b1a.w, b1b.x, b1b.y, b1b.z, b1b.w};

    #pragma unroll
    for (int k = 0; k < 8; ++k) {
        // B2 row k (uniform addr -> broadcast b128)
        const float4 b2a = *(const float4*)&buf[B2OFF + k * 8];
        const float4 b2b = *(const float4*)&buf[B2OFF + k * 8 + 4];
        // B3 row (j*8+k), transposed storage -> conflict-free b128
        const float4 b3a = *(const float4*)&buf[B3OFF + (k * 8 + j) * 12];
        const float4 b3b = *(const float4*)&buf[B3OFF + (k * 8 + j) * 12 + 4];
        // B4 own row, stride 68 -> conflict-free b128
        const float4 b4a = *(const float4*)&buf[B4OFF + lane * 68 + k * 8];
        const float4 b4b = *(const float4*)&buf[B4OFF + lane * 68 + k * 8 + 4];
        const float B2r[8] = {b2a.x, b2a.y, b2a.z, b2a.w, b2b.x, b2b.y, b2b.z, b2b.w};
        const float B3r[8] = {b3a.x, b3a.y, b3a.z, b3a.w, b3b.x, b3b.y, b3b.z, b3b.w};
        const float B4r[8] = {b4a.x, b4a.y, b4a.z, b4a.w, b4b.x, b4b.y, b4b.z, b4b.w};
        #pragma unroll
        for (int l = 0; l < 8; ++l)
            A4[k][l] += A3[k] * B1[l] + A2 * B2r[l] + A1 * B3r[l] + B4r[l];
    }
    // C3 = A3 + A2⊗B1 + A1⊗B2 + B3(own row)
    {
        const float4 o3a = *(const float4*)&buf[B3OFF + b3row(lane) * 12];
        const float4 o3b = *(const float4*)&buf[B3OFF + b3row(lane) * 12 + 4];
        const float O3[8] = {o3a.x, o3a.y, o3a.z, o3a.w, o3b.x, o3b.y, o3b.z, o3b.w};
        const float4 j2a = *(const float4*)&buf[B2OFF + j * 8];
        const float4 j2b = *(const float4*)&buf[B2OFF + j * 8 + 4];
        const float J2[8] = {j2a.x, j2a.y, j2a.z, j2a.w, j2b.x, j2b.y, j2b.z, j2b.w};
        #pragma unroll
        for (int k = 0; k < 8; ++k)
            A3[k] += A2 * B1[k] + A1 * J2[k] + O3[k];
    }
    // C2 = A2 + A1⊗B1 + B2 ; C1
    A2 += A1 * B1[j] + buf[B2OFF + lane];
    A1 += B1[i];
}

// ---------------------------------------------------------------------------
// Kernel 1: one block per (batch, quarter); 512 thr = 8 waves x 16-step scan.
// LDS = 41.5 KB (2 FATPAD-v2 buffers) -> 2 blocks/CU co-resident, 4 waves/
// SIMD. __launch_bounds__(512,4) caps VGPR at 128 (scan needs ~88).
// ---------------------------------------------------------------------------
__global__ __launch_bounds__(512, 4) void sig_quarter_kernel(const float* __restrict__ X,
                                                             float* __restrict__ sig) {
    const int blk = blockIdx.x;      // b * 4 + q
    const int b = blk >> 2, q = blk & 3;
    const int t = threadIdx.x;
    const int w = t >> 6;            // wave id == sub-chunk id (0..7)
    const int lane = t & 63;
    const int i = lane >> 3, j = lane & 7;
    const int s0base = q * 128;

    __shared__ __align__(16) float lds[2 * BUFSZ];     // 41.5 KB

    // ---- Phase 0: dx rows [s0base, s0base+128) -> lds[0..1023] (4 KB)
    {
        const float2* __restrict__ X2 =
            (const float2*)(X + ((size_t)b * LEN + s0base) * 8);
        float2 r = make_float2(0.f, 0.f);
        if (s0base + (t >> 2) < LEN - 1) {             // guard global row 511
            const float2 a = X2[t], c = X2[t + 4];
            r = make_float2(c.x - a.x, c.y - a.y);
        }
        ((float2*)lds)[t] = r;
    }
    __syncthreads();

    // ---- Phase 1: fat scan; wave w scans steps [s0, s0+nst) [R16-verified]
    float s1 = 0.f, s2 = 0.f;
    float s3[8] = {};
    float s4[8][8] = {};
    {
        const int s0 = s0base + w * 16;
        const int nst = (s0 + 16 <= LEN - 1) ? 16 : (LEN - 1 - s0);  // 15 last
        const v4f* __restrict__ Xv = (const v4f*)(X + (size_t)b * LEN * 8);
        v4f pA = Xv[s0 * 2], pB = Xv[s0 * 2 + 1];
        const v4f* __restrict__ Xn = Xv + (s0 + 1) * 2;
        const float* __restrict__ dxL = lds + (w * 16) * 8;
        #pragma unroll 4
        for (int s = 0; s < nst; ++s) {
            const v4f cA = Xn[s * 2], cB = Xn[s * 2 + 1];   // uniform VMEM
            const v4f dA = cA - pA, dB = cB - pB;
            pA = cA; pB = cB;
            const float vi = dxL[s * 8 + i];           // LDS broadcast
            const float vj = dxL[s * 8 + j];
            const float dv[8] = {dA.x, dA.y, dA.z, dA.w, dB.x, dB.y, dB.z, dB.w};

            const float t1 = s1 * vj;
            const float p  = vi * vj;
            const float u  = fmaf(1.f / 24.f, p, fmaf(1.f / 6.f, t1, 0.5f * s2));
            const float ww = fmaf(1.f / 6.f, p, fmaf(0.5f, t1, s2));
            float cc[8];
            #pragma unroll
            for (int k = 0; k < 8; ++k) {
                cc[k] = fmaf(dv[k], u, s3[k]);
                s3[k] = fmaf(dv[k], ww, s3[k]);
            }
            #pragma unroll
            for (int k = 0; k < 8; ++k) {
                #pragma unroll
                for (int l = 0; l < 8; ++l)
                    s4[k][l] = fmaf(cc[k], dv[l], s4[k][l]);
            }
            s2 = fmaf(0.5f, p, s2 + t1);
            s1 += vi;
        }
    }
    __syncthreads();            // dx region dead; lds becomes 2 sig buffers

    float* __restrict__ buf0 = lds;
    float* __restrict__ buf1 = lds + BUFSZ;

    // ---- Phase 2: 3-level pairwise Chen tree, 2-buffer schedule
    if (w == 1) stage_fat(buf0, s1, s2, s3, s4, lane);
    if (w == 3) stage_fat(buf1, s1, s2, s3, s4, lane);
    __syncthreads();
    if (w == 0) combine_fat(s1, s2, s3, s4, buf0, i, j, lane);   // C01
    if (w == 2) combine_fat(s1, s2, s3, s4, buf1, i, j, lane);   // C23
    __syncthreads();
    if (w == 5) stage_fat(buf0, s1, s2, s3, s4, lane);
    if (w == 7) stage_fat(buf1, s1, s2, s3, s4, lane);
    __syncthreads();
    if (w == 4) combine_fat(s1, s2, s3, s4, buf0, i, j, lane);   // C45
    if (w == 6) combine_fat(s1, s2, s3, s4, buf1, i, j, lane);   // C67
    __syncthreads();
    if (w == 2) stage_fat(buf0, s1, s2, s3, s4, lane);
    if (w == 6) stage_fat(buf1, s1, s2, s3, s4, lane);
    __syncthreads();
    if (w == 0) combine_fat(s1, s2, s3, s4, buf0, i, j, lane);   // C0123
    if (w == 4) combine_fat(s1, s2, s3, s4, buf1, i, j, lane);   // C4567
    __syncthreads();
    if (w == 4) stage_fat(buf0, s1, s2, s3, s4, lane);
    __syncthreads();
    if (w == 0) combine_fat(s1, s2, s3, s4, buf0, i, j, lane);   // full quarter
    __syncthreads();
    if (w == 0) stage_fat(buf0, s1, s2, s3, s4, lane);
    __syncthreads();

    // ---- Phase 3: write quarter-sig THIN to global (kernel-2 layout)
    float* __restrict__ o = sig + (size_t)blk * SIG_DIM;
    const int ij = t >> 3, kk = t & 7;
    if (t < 8)  o[t] = buf0[t];
    if (t < 64) o[OFF2 + t] = buf0[B2OFF + t];
    o[OFF3 + t] = buf0[B3OFF + b3row(ij) * 12 + kk];
    {
        const float* __restrict__ src = &buf0[B4OFF + ij * 68 + kk * 8];
        *(float4*)&o[OFF4 + t * 8] =
            make_float4(src[0], src[1], src[2], src[3]);
        *(float4*)&o[OFF4 + t * 8 + 4] =
            make_float4(src[4], src[5], src[6], src[7]);
    }
}

// ---------------------------------------------------------------------------
// Kernel 2 [R18-verified verbatim]: pairwise Chen-combine tree over 4 quarter
// signatures + fused linear + block reduction. 128 blocks x 512 threads.
// ---------------------------------------------------------------------------
__device__ __forceinline__ void chen_combine(float& A1, float& A2, float& A3,
                                             float A4[8],
                                             const float* __restrict__ B,
                                             int i, int j, int k, int t) {
    const float B1i = B[i], B1j = B[j], B1k = B[k];
    const float4 b1a = *(const float4*)&B[0];
    const float4 b1b = *(const float4*)&B[4];
    const float B2ij = B[OFF2 + i * 8 + j];
    const float B2jk = B[OFF2 + j * 8 + k];
    const float4 b2a = *(const float4*)&B[OFF2 + k * 8];
    const float4 b2b = *(const float4*)&B[OFF2 + k * 8 + 4];
    const float B3ijk = B[OFF3 + t];
    const float4 b3a = *(const float4*)&B[OFF3 + (j * 8 + k) * 8];
    const float4 b3b = *(const float4*)&B[OFF3 + (j * 8 + k) * 8 + 4];
    const float4 b4a = *(const float4*)&B[OFF4 + t * 8];
    const float4 b4b = *(const float4*)&B[OFF4 + t * 8 + 4];

    A4[0] += A3 * b1a.x + A2 * b2a.x + A1 * b3a.x + b4a.x;
    A4[1] += A3 * b1a.y + A2 * b2a.y + A1 * b3a.y + b4a.y;
    A4[2] += A3 * b1a.z + A2 * b2a.z + A1 * b3a.z + b4a.z;
    A4[3] += A3 * b1a.w + A2 * b2a.w + A1 * b3a.w + b4a.w;
    A4[4] += A3 * b1b.x + A2 * b2b.x + A1 * b3b.x + b4b.x;
    A4[5] += A3 * b1b.y + A2 * b2b.y + A1 * b3b.y + b4b.y;
    A4[6] += A3 * b1b.z + A2 * b2b.z + A1 * b3b.z + b4b.z;
    A4[7] += A3 * b1b.w + A2 * b2b.w + A1 * b3b.w + b4b.w;
    A3 += A2 * B1k + A1 * B2jk + B3ijk;
    A2 += A1 * B1j + B2ij;
    A1 += B1i;
}

__global__ __launch_bounds__(512) void sig_combine_linear(const float* __restrict__ sig,
                                                          const float* __restrict__ W,
                                                          const float* __restrict__ bias,
                                                          float* __restrict__ out) {
    const int b = blockIdx.x;
    const int t = threadIdx.x;
    const int i = t >> 6, j = (t >> 3) & 7, k = t & 7;
    const float* __restrict__ S = sig + (size_t)b * NCHUNK * SIG_DIM;

    // C01 = chunk0 ∘ chunk1
    float A1 = S[i];
    float A2 = S[OFF2 + i * 8 + j];
    float A3 = S[OFF3 + t];
    const float4 a4a = *(const float4*)&S[OFF4 + t * 8];
    const float4 a4b = *(const float4*)&S[OFF4 + t * 8 + 4];
    float A4[8] = {a4a.x, a4a.y, a4a.z, a4a.w, a4b.x, a4b.y, a4b.z, a4b.w};
    chen_combine(A1, A2, A3, A4, S + SIG_DIM, i, j, k, t);

    // C23 = chunk2 ∘ chunk3  (independent -> ILP)
    const float* __restrict__ S2 = S + 2 * SIG_DIM;
    float C1 = S2[i];
    float C2 = S2[OFF2 + i * 8 + j];
    float C3 = S2[OFF3 + t];
    const float4 c4a = *(const float4*)&S2[OFF4 + t * 8];
    const float4 c4b = *(const float4*)&S2[OFF4 + t * 8 + 4];
    float C4[8] = {c4a.x, c4a.y, c4a.z, c4a.w, c4b.x, c4b.y, c4b.z, c4b.w};
    chen_combine(C1, C2, C3, C4, S2 + SIG_DIM, i, j, k, t);

    // stage C23 to LDS (canonical owners, thin layout)
    __shared__ __align__(16) float Bs[SIG_DIM];
    if ((t & 63) == 0) Bs[t >> 6] = C1;
    if ((t & 7) == 0)  Bs[OFF2 + (t >> 3)] = C2;
    Bs[OFF3 + t] = C3;
    *(float4*)&Bs[OFF4 + t * 8]     = make_float4(C4[0], C4[1], C4[2], C4[3]);
    *(float4*)&Bs[OFF4 + t * 8 + 4] = make_float4(C4[4], C4[5], C4[6], C4[7]);
    __syncthreads();

    // C = C01 ∘ C23
    chen_combine(A1, A2, A3, A4, Bs, i, j, k, t);

    // Fused linear: out[b][n] = sum_d sig[d] * W[n][d] + bias[n]
    float part[N_OUT];
    #pragma unroll
    for (int n = 0; n < N_OUT; ++n) {
        const float* __restrict__ Wn = W + (size_t)n * SIG_DIM;
        float p = A3 * Wn[OFF3 + t];
        const float4 w4a = *(const float4*)&Wn[OFF4 + t * 8];
        const float4 w4b = *(const float4*)&Wn[OFF4 + t * 8 + 4];
        p = fmaf(A4[0], w4a.x, p);
        p = fmaf(A4[1], w4a.y, p);
        p = fmaf(A4[2], w4a.z, p);
        p = fmaf(A4[3], w4a.w, p);
        p = fmaf(A4[4], w4b.x, p);
        p = fmaf(A4[5], w4b.y, p);
        p = fmaf(A4[6], w4b.z, p);
        p = fmaf(A4[7], w4b.w, p);
        if ((t & 7) == 0)  p = fmaf(A2, Wn[OFF2 + (t >> 3)], p);
        if ((t & 63) == 0) p = fmaf(A1, Wn[t >> 6], p);
        part[n] = p;
    }

    #pragma unroll
    for (int n = 0; n < N_OUT; ++n) {
        #pragma unroll
        for (int off = 32; off > 0; off >>= 1)
            part[n] += __shfl_xor(part[n], off, 64);
    }
    __shared__ float red[8][N_OUT];
    const int wv = t >> 6, ln = t & 63;
    if (ln == 0) {
        #pragma unroll
        for (int n = 0; n < N_OUT; ++n) red[wv][n] = part[n];
    }
    __syncthreads();
    if (t < N_OUT) {
        float s = bias[t];
        #pragma unroll
        for (int w = 0; w < 8; ++w) s += red[w][t];
        out[b * N_OUT + t] = s;
    }
}

extern "C" void kernel_launch(void* const* d_in, const int* in_sizes, int n_in,
                              void* d_out, int out_size, void* d_ws, size_t ws_size,
                              hipStream_t stream) {
    const float* X    = (const float*)d_in[0];
    const float* W    = (const float*)d_in[1];
    const float* bias = (const float*)d_in[2];
    float* out = (float*)d_out;
    float* sig = (float*)d_ws;                 // 512*SIG_DIM*4 ≈ 9.6 MB

    hipLaunchKernelGGL(sig_quarter_kernel, dim3(BATCH * NCHUNK), dim3(512), 0, stream, X, sig);
    hipLaunchKernelGGL(sig_combine_linear, dim3(BATCH), dim3(512), 0, stream, sig, W, bias, out);
}

// Round 22
// 41.625 us; speedup vs baseline: 1.7565x; 1.7565x over previous
//
#include <hip/hip_runtime.h>

#define BATCH 128
#define LEN 512
#define NCHUNK 4              // quarters per batch (kernel-2 view)
#define SIG_DIM 4680          // 8 + 64 + 512 + 4096
#define N_OUT 10
// thin sig offsets (global layout, W indexing)
#define OFF2 8
#define OFF3 72
#define OFF4 584
// FATPAD v2 LDS sig buffer: B1[8] | B2[64] | B3[64 rows x 12 pad, rows
// bit-swap-permuted] | B4[64 rows x 68 pad]. All row reads/writes are
// conflict-free ds_read/write_b128 (12*j mod 32 and 68*lane mod 32 both
// enumerate the 8 four-bank groups). [R21-verified correct]
#define B2OFF 8
#define B3OFF 72
#define B4OFF 840
#define BUFSZ 5192            // 8 + 64 + 768 + 4352

typedef float v4f __attribute__((ext_vector_type(4)));

__device__ __forceinline__ int b3row(int r) {      // bit-swapped B3 row perm
    return ((r & 7) << 3) | (r >> 3);
}

// stage a fat-layout signature (lane=(i,j) owns s2, s3[k], s4[k][l]) into a
// FATPAD v2 LDS buffer. b128 writes throughout. [R21-verified]
__device__ __forceinline__ void stage_fat(float* __restrict__ buf,
                                          float s1, float s2,
                                          const float s3[8], const float s4[8][8],
                                          int lane) {
    if ((lane & 7) == 0) buf[lane >> 3] = s1;          // B1[i] (j==0 canonical)
    buf[B2OFF + lane] = s2;                            // B2[ij]
    const int pr = b3row(lane);
    *(float4*)&buf[B3OFF + pr * 12]     = make_float4(s3[0], s3[1], s3[2], s3[3]);
    *(float4*)&buf[B3OFF + pr * 12 + 4] = make_float4(s3[4], s3[5], s3[6], s3[7]);
    #pragma unroll
    for (int k = 0; k < 8; ++k) {
        float* dst = &buf[B4OFF + lane * 68 + k * 8];
        *(float4*)dst       = make_float4(s4[k][0], s4[k][1], s4[k][2], s4[k][3]);
        *(float4*)(dst + 4) = make_float4(s4[k][4], s4[k][5], s4[k][6], s4[k][7]);
    }
}

// Chen combine in fat layout: A (regs, earlier chunk) ∘= B (FATPAD v2 LDS).
// [R21-verified]
__device__ __forceinline__ void combine_fat(float& A1, float& A2,
                                            float A3[8], float A4[8][8],
                                            const float* __restrict__ buf,
                                            int i, int j, int lane) {
    const float4 b1a = *(const float4*)&buf[0];
    const float4 b1b = *(const float4*)&buf[4];
    const float B1[8] = {b1a.x, b1a.y, b1a.z, b1a.w, b1b.x, b1b.y, b1b.z, b1b.w};

    #pragma unroll
    for (int k = 0; k < 8; ++k) {
        const float4 b2a = *(const float4*)&buf[B2OFF + k * 8];
        const float4 b2b = *(const float4*)&buf[B2OFF + k * 8 + 4];
        const float4 b3a = *(const float4*)&buf[B3OFF + (k * 8 + j) * 12];
        const float4 b3b = *(const float4*)&buf[B3OFF + (k * 8 + j) * 12 + 4];
        const float4 b4a = *(const float4*)&buf[B4OFF + lane * 68 + k * 8];
        const float4 b4b = *(const float4*)&buf[B4OFF + lane * 68 + k * 8 + 4];
        const float B2r[8] = {b2a.x, b2a.y, b2a.z, b2a.w, b2b.x, b2b.y, b2b.z, b2b.w};
        const float B3r[8] = {b3a.x, b3a.y, b3a.z, b3a.w, b3b.x, b3b.y, b3b.z, b3b.w};
        const float B4r[8] = {b4a.x, b4a.y, b4a.z, b4a.w, b4b.x, b4b.y, b4b.z, b4b.w};
        #pragma unroll
        for (int l = 0; l < 8; ++l)
            A4[k][l] += A3[k] * B1[l] + A2 * B2r[l] + A1 * B3r[l] + B4r[l];
    }
    {
        const float4 o3a = *(const float4*)&buf[B3OFF + b3row(lane) * 12];
        const float4 o3b = *(const float4*)&buf[B3OFF + b3row(lane) * 12 + 4];
        const float O3[8] = {o3a.x, o3a.y, o3a.z, o3a.w, o3b.x, o3b.y, o3b.z, o3b.w};
        const float4 j2a = *(const float4*)&buf[B2OFF + j * 8];
        const float4 j2b = *(const float4*)&buf[B2OFF + j * 8 + 4];
        const float J2[8] = {j2a.x, j2a.y, j2a.z, j2a.w, j2b.x, j2b.y, j2b.z, j2b.w};
        #pragma unroll
        for (int k = 0; k < 8; ++k)
            A3[k] += A2 * B1[k] + A1 * J2[k] + O3[k];
    }
    A2 += A1 * B1[j] + buf[B2OFF + lane];
    A1 += B1[i];
}

// ---------------------------------------------------------------------------
// Kernel 1: one block per (batch, quarter); 512 thr = 8 waves x 16-step scan.
// LDS = 41.5 KB (2 FATPAD-v2 buffers) -> 2 blocks/CU co-resident at the
// natural VGPR~88 occupancy (4 waves/SIMD). PLAIN __launch_bounds__(512):
// R17/R19/R21 proved any min-waves declaration caps VGPR at 64 -> spill.
// ---------------------------------------------------------------------------
__global__ __launch_bounds__(512) void sig_quarter_kernel(const float* __restrict__ X,
                                                          float* __restrict__ sig) {
    const int blk = blockIdx.x;      // b * 4 + q
    const int b = blk >> 2, q = blk & 3;
    const int t = threadIdx.x;
    const int w = t >> 6;            // wave id == sub-chunk id (0..7)
    const int lane = t & 63;
    const int i = lane >> 3, j = lane & 7;
    const int s0base = q * 128;

    __shared__ __align__(16) float lds[2 * BUFSZ];     // 41.5 KB

    // ---- Phase 0: dx rows [s0base, s0base+128) -> lds[0..1023] (4 KB)
    {
        const float2* __restrict__ X2 =
            (const float2*)(X + ((size_t)b * LEN + s0base) * 8);
        float2 r = make_float2(0.f, 0.f);
        if (s0base + (t >> 2) < LEN - 1) {             // guard global row 511
            const float2 a = X2[t], c = X2[t + 4];
            r = make_float2(c.x - a.x, c.y - a.y);
        }
        ((float2*)lds)[t] = r;
    }
    __syncthreads();

    // ---- Phase 1: fat scan; wave w scans steps [s0, s0+nst) [R16-verified]
    float s1 = 0.f, s2 = 0.f;
    float s3[8] = {};
    float s4[8][8] = {};
    {
        const int s0 = s0base + w * 16;
        const int nst = (s0 + 16 <= LEN - 1) ? 16 : (LEN - 1 - s0);  // 15 last
        const v4f* __restrict__ Xv = (const v4f*)(X + (size_t)b * LEN * 8);
        v4f pA = Xv[s0 * 2], pB = Xv[s0 * 2 + 1];
        const v4f* __restrict__ Xn = Xv + (s0 + 1) * 2;
        const float* __restrict__ dxL = lds + (w * 16) * 8;
        #pragma unroll 4
        for (int s = 0; s < nst; ++s) {
            const v4f cA = Xn[s * 2], cB = Xn[s * 2 + 1];   // uniform VMEM
            const v4f dA = cA - pA, dB = cB - pB;
            pA = cA; pB = cB;
            const float vi = dxL[s * 8 + i];           // LDS broadcast
            const float vj = dxL[s * 8 + j];
            const float dv[8] = {dA.x, dA.y, dA.z, dA.w, dB.x, dB.y, dB.z, dB.w};

            const float t1 = s1 * vj;
            const float p  = vi * vj;
            const float u  = fmaf(1.f / 24.f, p, fmaf(1.f / 6.f, t1, 0.5f * s2));
            const float ww = fmaf(1.f / 6.f, p, fmaf(0.5f, t1, s2));
            float cc[8];
            #pragma unroll
            for (int k = 0; k < 8; ++k) {
                cc[k] = fmaf(dv[k], u, s3[k]);
                s3[k] = fmaf(dv[k], ww, s3[k]);
            }
            #pragma unroll
            for (int k = 0; k < 8; ++k) {
                #pragma unroll
                for (int l = 0; l < 8; ++l)
                    s4[k][l] = fmaf(cc[k], dv[l], s4[k][l]);
            }
            s2 = fmaf(0.5f, p, s2 + t1);
            s1 += vi;
        }
    }
    __syncthreads();            // dx region dead; lds becomes 2 sig buffers

    float* __restrict__ buf0 = lds;
    float* __restrict__ buf1 = lds + BUFSZ;

    // ---- Phase 2: 3-level pairwise Chen tree, 2-buffer schedule [R21-verified]
    if (w == 1) stage_fat(buf0, s1, s2, s3, s4, lane);
    if (w == 3) stage_fat(buf1, s1, s2, s3, s4, lane);
    __syncthreads();
    if (w == 0) combine_fat(s1, s2, s3, s4, buf0, i, j, lane);   // C01
    if (w == 2) combine_fat(s1, s2, s3, s4, buf1, i, j, lane);   // C23
    __syncthreads();
    if (w == 5) stage_fat(buf0, s1, s2, s3, s4, lane);
    if (w == 7) stage_fat(buf1, s1, s2, s3, s4, lane);
    __syncthreads();
    if (w == 4) combine_fat(s1, s2, s3, s4, buf0, i, j, lane);   // C45
    if (w == 6) combine_fat(s1, s2, s3, s4, buf1, i, j, lane);   // C67
    __syncthreads();
    if (w == 2) stage_fat(buf0, s1, s2, s3, s4, lane);
    if (w == 6) stage_fat(buf1, s1, s2, s3, s4, lane);
    __syncthreads();
    if (w == 0) combine_fat(s1, s2, s3, s4, buf0, i, j, lane);   // C0123
    if (w == 4) combine_fat(s1, s2, s3, s4, buf1, i, j, lane);   // C4567
    __syncthreads();
    if (w == 4) stage_fat(buf0, s1, s2, s3, s4, lane);
    __syncthreads();
    if (w == 0) combine_fat(s1, s2, s3, s4, buf0, i, j, lane);   // full quarter
    __syncthreads();
    if (w == 0) stage_fat(buf0, s1, s2, s3, s4, lane);
    __syncthreads();

    // ---- Phase 3: write quarter-sig THIN to global [R21-verified]
    float* __restrict__ o = sig + (size_t)blk * SIG_DIM;
    const int ij = t >> 3, kk = t & 7;
    if (t < 8)  o[t] = buf0[t];
    if (t < 64) o[OFF2 + t] = buf0[B2OFF + t];
    o[OFF3 + t] = buf0[B3OFF + b3row(ij) * 12 + kk];
    {
        const float* __restrict__ src = &buf0[B4OFF + ij * 68 + kk * 8];
        *(float4*)&o[OFF4 + t * 8] =
            make_float4(src[0], src[1], src[2], src[3]);
        *(float4*)&o[OFF4 + t * 8 + 4] =
            make_float4(src[4], src[5], src[6], src[7]);
    }
}

// ---------------------------------------------------------------------------
// Kernel 2 [R18-verified verbatim]: pairwise Chen-combine tree over 4 quarter
// signatures + fused linear + block reduction. 128 blocks x 512 threads.
// ---------------------------------------------------------------------------
__device__ __forceinline__ void chen_combine(float& A1, float& A2, float& A3,
                                             float A4[8],
                                             const float* __restrict__ B,
                                             int i, int j, int k, int t) {
    const float B1i = B[i], B1j = B[j], B1k = B[k];
    const float4 b1a = *(const float4*)&B[0];
    const float4 b1b = *(const float4*)&B[4];
    const float B2ij = B[OFF2 + i * 8 + j];
    const float B2jk = B[OFF2 + j * 8 + k];
    const float4 b2a = *(const float4*)&B[OFF2 + k * 8];
    const float4 b2b = *(const float4*)&B[OFF2 + k * 8 + 4];
    const float B3ijk = B[OFF3 + t];
    const float4 b3a = *(const float4*)&B[OFF3 + (j * 8 + k) * 8];
    const float4 b3b = *(const float4*)&B[OFF3 + (j * 8 + k) * 8 + 4];
    const float4 b4a = *(const float4*)&B[OFF4 + t * 8];
    const float4 b4b = *(const float4*)&B[OFF4 + t * 8 + 4];

    A4[0] += A3 * b1a.x + A2 * b2a.x + A1 * b3a.x + b4a.x;
    A4[1] += A3 * b1a.y + A2 * b2a.y + A1 * b3a.y + b4a.y;
    A4[2] += A3 * b1a.z + A2 * b2a.z + A1 * b3a.z + b4a.z;
    A4[3] += A3 * b1a.w + A2 * b2a.w + A1 * b3a.w + b4a.w;
    A4[4] += A3 * b1b.x + A2 * b2b.x + A1 * b3b.x + b4b.x;
    A4[5] += A3 * b1b.y + A2 * b2b.y + A1 * b3b.y + b4b.y;
    A4[6] += A3 * b1b.z + A2 * b2b.z + A1 * b3b.z + b4b.z;
    A4[7] += A3 * b1b.w + A2 * b2b.w + A1 * b3b.w + b4b.w;
    A3 += A2 * B1k + A1 * B2jk + B3ijk;
    A2 += A1 * B1j + B2ij;
    A1 += B1i;
}

__global__ __launch_bounds__(512) void sig_combine_linear(const float* __restrict__ sig,
                                                          const float* __restrict__ W,
                                                          const float* __restrict__ bias,
                                                          float* __restrict__ out) {
    const int b = blockIdx.x;
    const int t = threadIdx.x;
    const int i = t >> 6, j = (t >> 3) & 7, k = t & 7;
    const float* __restrict__ S = sig + (size_t)b * NCHUNK * SIG_DIM;

    // C01 = chunk0 ∘ chunk1
    float A1 = S[i];
    float A2 = S[OFF2 + i * 8 + j];
    float A3 = S[OFF3 + t];
    const float4 a4a = *(const float4*)&S[OFF4 + t * 8];
    const float4 a4b = *(const float4*)&S[OFF4 + t * 8 + 4];
    float A4[8] = {a4a.x, a4a.y, a4a.z, a4a.w, a4b.x, a4b.y, a4b.z, a4b.w};
    chen_combine(A1, A2, A3, A4, S + SIG_DIM, i, j, k, t);

    // C23 = chunk2 ∘ chunk3  (independent -> ILP)
    const float* __restrict__ S2 = S + 2 * SIG_DIM;
    float C1 = S2[i];
    float C2 = S2[OFF2 + i * 8 + j];
    float C3 = S2[OFF3 + t];
    const float4 c4a = *(const float4*)&S2[OFF4 + t * 8];
    const float4 c4b = *(const float4*)&S2[OFF4 + t * 8 + 4];
    float C4[8] = {c4a.x, c4a.y, c4a.z, c4a.w, c4b.x, c4b.y, c4b.z, c4b.w};
    chen_combine(C1, C2, C3, C4, S2 + SIG_DIM, i, j, k, t);

    // stage C23 to LDS (canonical owners, thin layout)
    __shared__ __align__(16) float Bs[SIG_DIM];
    if ((t & 63) == 0) Bs[t >> 6] = C1;
    if ((t & 7) == 0)  Bs[OFF2 + (t >> 3)] = C2;
    Bs[OFF3 + t] = C3;
    *(float4*)&Bs[OFF4 + t * 8]     = make_float4(C4[0], C4[1], C4[2], C4[3]);
    *(float4*)&Bs[OFF4 + t * 8 + 4] = make_float4(C4[4], C4[5], C4[6], C4[7]);
    __syncthreads();

    // C = C01 ∘ C23
    chen_combine(A1, A2, A3, A4, Bs, i, j, k, t);

    // Fused linear: out[b][n] = sum_d sig[d] * W[n][d] + bias[n]
    float part[N_OUT];
    #pragma unroll
    for (int n = 0; n < N_OUT; ++n) {
        const float* __restrict__ Wn = W + (size_t)n * SIG_DIM;
        float p = A3 * Wn[OFF3 + t];
        const float4 w4a = *(const float4*)&Wn[OFF4 + t * 8];
        const float4 w4b = *(const float4*)&Wn[OFF4 + t * 8 + 4];
        p = fmaf(A4[0], w4a.x, p);
        p = fmaf(A4[1], w4a.y, p);
        p = fmaf(A4[2], w4a.z, p);
        p = fmaf(A4[3], w4a.w, p);
        p = fmaf(A4[4], w4b.x, p);
        p = fmaf(A4[5], w4b.y, p);
        p = fmaf(A4[6], w4b.z, p);
        p = fmaf(A4[7], w4b.w, p);
        if ((t & 7) == 0)  p = fmaf(A2, Wn[OFF2 + (t >> 3)], p);
        if ((t & 63) == 0) p = fmaf(A1, Wn[t >> 6], p);
        part[n] = p;
    }

    #pragma unroll
    for (int n = 0; n < N_OUT; ++n) {
        #pragma unroll
        for (int off = 32; off > 0; off >>= 1)
            part[n] += __shfl_xor(part[n], off, 64);
    }
    __shared__ float red[8][N_OUT];
    const int wv = t >> 6, ln = t & 63;
    if (ln == 0) {
        #pragma unroll
        for (int n = 0; n < N_OUT; ++n) red[wv][n] = part[n];
    }
    __syncthreads();
    if (t < N_OUT) {
        float s = bias[t];
        #pragma unroll
        for (int w = 0; w < 8; ++w) s += red[w][t];
        out[b * N_OUT + t] = s;
    }
}

extern "C" void kernel_launch(void* const* d_in, const int* in_sizes, int n_in,
                              void* d_out, int out_size, void* d_ws, size_t ws_size,
                              hipStream_t stream) {
    const float* X    = (const float*)d_in[0];
    const float* W    = (const float*)d_in[1];
    const float* bias = (const float*)d_in[2];
    float* out = (float*)d_out;
    float* sig = (float*)d_ws;                 // 512*SIG_DIM*4 ≈ 9.6 MB

    hipLaunchKernelGGL(sig_quarter_kernel, dim3(BATCH * NCHUNK), dim3(512), 0, stream, X, sig);
    hipLaunchKernelGGL(sig_combine_linear, dim3(BATCH), dim3(512), 0, stream, sig, W, bias, out);
}